// Round 4
// baseline (62.344 us; speedup 1.0000x reference)
//
#include <hip/hip_runtime.h>

typedef short bf16x4 __attribute__((ext_vector_type(4)));
typedef short bf16x8 __attribute__((ext_vector_type(8)));
typedef float f32x4 __attribute__((ext_vector_type(4)));
typedef unsigned short u16x4 __attribute__((ext_vector_type(4)));
typedef unsigned short u16x8 __attribute__((ext_vector_type(8)));

__device__ __forceinline__ unsigned short f2bf(float f) {
  union { float f; unsigned u; } v; v.f = f;
  unsigned r = v.u + 0x7FFFu + ((v.u >> 16) & 1u);
  return (unsigned short)(r >> 16);
}
__device__ __forceinline__ unsigned fbits(float f) {
  union { float f; unsigned u; } x; x.f = f; return x.u;
}
__device__ __forceinline__ float bfloat(unsigned u) {
  union { unsigned u; float f; } x; x.u = u; return x.f;
}
__device__ __forceinline__ float fexp2(float x) {
#if __has_builtin(__builtin_amdgcn_exp2f)
  return __builtin_amdgcn_exp2f(x);
#else
  return exp2f(x);
#endif
}
__device__ __forceinline__ f32x4 pv_mfma(bf16x4 a, bf16x4 b, f32x4 c) {
#if __has_builtin(__builtin_amdgcn_mfma_f32_16x16x16bf16_1k)
  return __builtin_amdgcn_mfma_f32_16x16x16bf16_1k(a, b, c, 0, 0, 0);
#else
  bf16x8 az = {a[0], a[1], a[2], a[3], 0, 0, 0, 0};
  bf16x8 bz = {b[0], b[1], b[2], b[3], 0, 0, 0, 0};
  return __builtin_amdgcn_mfma_f32_16x16x32_bf16(az, bz, c, 0, 0, 0);
#endif
}

// ---------- cast/transpose: Xq,Xkv [128][4096] f32 -> XT [2][4096][128] bf16,
// ---------- plus weight casts (wqkv -> bf16, wproj -> hi/lo bf16 split).
__global__ __launch_bounds__(256)
void cast_kernel(const float* __restrict__ Xq, const float* __restrict__ Xkv,
                 const float* __restrict__ Wqkv, const float* __restrict__ Wproj,
                 unsigned short* __restrict__ XT, unsigned short* __restrict__ Wq16,
                 unsigned short* __restrict__ Wph, unsigned short* __restrict__ Wpl)
{
  const int b = blockIdx.x, t = threadIdx.x;
  if (b < 256) {
    __shared__ __align__(16) float Tl[64][68];
    const int img = b >> 7, kt = (b >> 6) & 1, nt = b & 63;
    const float* X = img ? Xkv : Xq;
    #pragma unroll
    for (int i = 0; i < 4; ++i) {
      int e = i * 256 + t;
      int r = e >> 4, c4 = (e & 15) * 4;
      *(f32x4*)&Tl[r][c4] = *(const f32x4*)&X[(kt * 64 + r) * 4096 + nt * 64 + c4];
    }
    __syncthreads();
    unsigned short* out = XT + img * (4096 * 128);
    #pragma unroll
    for (int i = 0; i < 2; ++i) {
      int u = i * 256 + t;
      int n = u >> 3, kg = u & 7;
      u16x8 tv;
      #pragma unroll
      for (int j = 0; j < 8; ++j) tv[j] = f2bf(Tl[kg * 8 + j][n]);
      *(u16x8*)&out[(nt * 64 + n) * 128 + kt * 64 + kg * 8] = tv;
    }
  } else {
    const int wb = b - 256;
    if (wb < 3) {
      #pragma unroll 4
      for (int i = 0; i < 64; ++i) {
        int idx = wb * 16384 + i * 256 + t;
        Wq16[idx] = f2bf(Wqkv[idx]);
      }
    } else {
      #pragma unroll 4
      for (int i = 0; i < 64; ++i) {
        int idx = i * 256 + t;
        float v = Wproj[idx];
        unsigned short h = f2bf(v);
        float hf = bfloat((unsigned)h << 16);
        Wph[idx] = h;
        Wpl[idx] = f2bf(v - hf);
      }
    }
  }
}

// ---------- qkv GEMM: Y[o][n] = sum_k W[o][k]*X[k][n], all-register MFMA,
// ---------- bf16 output (feeds dwconv).
__global__ __launch_bounds__(256)
void gemm_qkv_kernel(const unsigned short* __restrict__ XT,
                     const unsigned short* __restrict__ Wq16,
                     unsigned short* __restrict__ Y16)
{
  const int t = threadIdx.x;
  const int w = t >> 6, c = t & 15, g = (t & 63) >> 4;
  const int n0 = blockIdx.x * 32;
  const int ob = blockIdx.y;                 // 0..5; ob>=2 -> Xkv
  const int o_base = ob * 64 + w * 16;
  const unsigned short* B = XT + (ob >= 2 ? 4096 * 128 : 0);
  f32x4 acc0 = {0.f, 0.f, 0.f, 0.f}, acc1 = {0.f, 0.f, 0.f, 0.f};
  #pragma unroll
  for (int ks = 0; ks < 4; ++ks) {
    bf16x8 a = *(const bf16x8*)&Wq16[(o_base + c) * 128 + ks * 32 + g * 8];
    bf16x8 b0 = *(const bf16x8*)&B[(n0 + c) * 128 + ks * 32 + g * 8];
    bf16x8 b1 = *(const bf16x8*)&B[(n0 + 16 + c) * 128 + ks * 32 + g * 8];
    acc0 = __builtin_amdgcn_mfma_f32_16x16x32_bf16(a, b0, acc0, 0, 0, 0);
    acc1 = __builtin_amdgcn_mfma_f32_16x16x32_bf16(a, b1, acc1, 0, 0, 0);
  }
  #pragma unroll
  for (int i = 0; i < 4; ++i) {
    Y16[(o_base + 4 * g + i) * 4096 + n0 + c] = f2bf(acc0[i]);
    Y16[(o_base + 4 * g + i) * 4096 + n0 + 16 + c] = f2bf(acc1[i]);
  }
}

// ---------- proj GEMM, split-bf16 (hi+lo) for f32-quality output ----------
__global__ __launch_bounds__(256)
void gemm_proj_kernel(const unsigned short* __restrict__ Oth,
                      const unsigned short* __restrict__ Otl,
                      const unsigned short* __restrict__ Wph,
                      const unsigned short* __restrict__ Wpl, float* __restrict__ Y)
{
  const int t = threadIdx.x;
  const int w = t >> 6, c = t & 15, g = (t & 63) >> 4;
  const int n0 = blockIdx.x * 32;
  const int o_base = blockIdx.y * 64 + w * 16;
  f32x4 acc0 = {0.f, 0.f, 0.f, 0.f}, acc1 = {0.f, 0.f, 0.f, 0.f};
  #pragma unroll
  for (int ks = 0; ks < 4; ++ks) {
    const int ko = ks * 32 + g * 8;
    bf16x8 ah = *(const bf16x8*)&Wph[(o_base + c) * 128 + ko];
    bf16x8 al = *(const bf16x8*)&Wpl[(o_base + c) * 128 + ko];
    bf16x8 bh0 = *(const bf16x8*)&Oth[(n0 + c) * 128 + ko];
    bf16x8 bl0 = *(const bf16x8*)&Otl[(n0 + c) * 128 + ko];
    bf16x8 bh1 = *(const bf16x8*)&Oth[(n0 + 16 + c) * 128 + ko];
    bf16x8 bl1 = *(const bf16x8*)&Otl[(n0 + 16 + c) * 128 + ko];
    acc0 = __builtin_amdgcn_mfma_f32_16x16x32_bf16(al, bh0, acc0, 0, 0, 0);
    acc0 = __builtin_amdgcn_mfma_f32_16x16x32_bf16(ah, bl0, acc0, 0, 0, 0);
    acc0 = __builtin_amdgcn_mfma_f32_16x16x32_bf16(ah, bh0, acc0, 0, 0, 0);
    acc1 = __builtin_amdgcn_mfma_f32_16x16x32_bf16(al, bh1, acc1, 0, 0, 0);
    acc1 = __builtin_amdgcn_mfma_f32_16x16x32_bf16(ah, bl1, acc1, 0, 0, 0);
    acc1 = __builtin_amdgcn_mfma_f32_16x16x32_bf16(ah, bh1, acc1, 0, 0, 0);
  }
  #pragma unroll
  for (int i = 0; i < 4; ++i) {
    Y[(o_base + 4 * g + i) * 4096 + n0 + c] = acc0[i];
    Y[(o_base + 4 * g + i) * 4096 + n0 + 16 + c] = acc1[i];
  }
}

// ------------- depthwise 3x3 SAME on one 64x64 plane per block -------------
// bf16 in (from qkv GEMM), bf16 out; temperature*log2e folded into q channels.
__global__ __launch_bounds__(256)
void dwconv_kernel(const unsigned short* __restrict__ T16, const float* __restrict__ Wd,
                   const float* __restrict__ temp, unsigned short* __restrict__ Qb)
{
  __shared__ __align__(16) float P[4096];
  const int jc = blockIdx.x;
  const int t = threadIdx.x;
  const unsigned short* in = T16 + jc * 4096;
  #pragma unroll
  for (int i = 0; i < 2; ++i) {
    u16x8 v = *(const u16x8*)&in[(i * 256 + t) * 8];
    #pragma unroll
    for (int j = 0; j < 8; ++j)
      P[(i * 256 + t) * 8 + j] = bfloat((unsigned)v[j] << 16);
  }
  float w[9];
  #pragma unroll
  for (int k = 0; k < 9; ++k) w[k] = Wd[jc * 9 + k];
  const float scale = (jc < 128) ? temp[jc >> 5] * 1.4426950408889634f : 1.0f;
  __syncthreads();
  unsigned short* out = Qb + jc * 4096;
  #pragma unroll 4
  for (int i = 0; i < 16; ++i) {
    int idx = i * 256 + t;
    int y = idx >> 6, x = idx & 63;
    float acc = 0.f;
    #pragma unroll
    for (int dy = -1; dy <= 1; ++dy) {
      int yy = y + dy;
      if (yy < 0 || yy > 63) continue;
      #pragma unroll
      for (int dx = -1; dx <= 1; ++dx) {
        int xx = x + dx;
        if (xx < 0 || xx > 63) continue;
        acc += w[(dy + 1) * 3 + (dx + 1)] * P[yy * 64 + xx];
      }
    }
    out[idx] = f2bf(acc * scale);
  }
}

// ----------------------- flash attention (bf16 MFMA) -----------------------
// Block = 64 queries x 4 key-split groups (1024 thr). Each wave handles ALL
// 64 queries (qf[4] subtiles) for 2 of its group's 8 key-chunks per tile ->
// one K/V LDS fragment read feeds 4 QK + 8 PV MFMAs (4x less LDS traffic).
// Partials: 16 waves -> 4-round in-group LDS accumulate, then cross-group sum.
#define KOFF (128 * 4096)
#define VOFF (256 * 4096)
#define KSTR 40
#define VSTR 132

__global__ __launch_bounds__(1024, 4)
void attn_kernel(const unsigned short* __restrict__ Qb,
                 unsigned short* __restrict__ Oth, unsigned short* __restrict__ Otl)
{
  __shared__ __align__(16) char lds[74752];
  unsigned short* Kg = (unsigned short*)lds;             // [4][128][40] u16
  unsigned short* Vg = (unsigned short*)(lds + 40960);   // [4][32][132] u16
  const int t = threadIdx.x;
  const int g4 = t >> 8;          // key-split group 0..3
  const int ts = t & 255;
  const int qw = (t >> 6) & 3;    // chunk-split wave within group
  const int l = t & 63;
  const int c = l & 15, g = l >> 4;
  const int h = blockIdx.y;
  const int nq = blockIdx.x * 64;

  unsigned short* Kgg = Kg + g4 * (128 * KSTR);
  unsigned short* Vgg = Vg + g4 * (32 * VSTR);

  // 4 Q B-frags: subtile s covers queries nq + s*16 + c
  bf16x8 qf[4];
  #pragma unroll
  for (int s = 0; s < 4; ++s)
    #pragma unroll
    for (int e = 0; e < 8; ++e)
      qf[s][e] = (short)Qb[(h * 32 + g * 8 + e) * 4096 + nq + s * 16 + c];

  f32x4 oh[4][2];
  #pragma unroll
  for (int s = 0; s < 4; ++s) {
    oh[s][0] = (f32x4){0.f, 0.f, 0.f, 0.f};
    oh[s][1] = (f32x4){0.f, 0.f, 0.f, 0.f};
  }
  float lsum[4] = {0.f, 0.f, 0.f, 0.f};

  const int kdp = ts >> 4;
  const int kj  = ts & 15;
  const int vdd = ts >> 4;
  const int vj  = ts & 15;

  u16x4 kr0[2], kr1[2];
  u16x8 vr[2];
  {
    const int m0 = g4 * 128;
    #pragma unroll
    for (int it = 0; it < 2; ++it) {
      int m = kj * 4 + it * 64;
      kr0[it] = *(const u16x4*)&Qb[KOFF + (h * 32 + 2 * kdp) * 4096 + m0 + m];
      kr1[it] = *(const u16x4*)&Qb[KOFF + (h * 32 + 2 * kdp + 1) * 4096 + m0 + m];
      vr[it] = *(const u16x8*)&Qb[VOFF + (h * 32 + vdd + 16 * it) * 4096 + m0 + vj * 8];
    }
  }

  for (int tt = 0; tt < 8; ++tt) {
    __syncthreads();
    #pragma unroll
    for (int it = 0; it < 2; ++it) {
      int m = kj * 4 + it * 64;
      #pragma unroll
      for (int i = 0; i < 4; ++i)
        *(unsigned*)&Kgg[(m + i) * KSTR + 2 * kdp] =
            (unsigned)kr0[it][i] | ((unsigned)kr1[it][i] << 16);
      int d = vdd + 16 * it;
      *(u16x4*)&Vgg[d * VSTR + vj * 8] =
          __builtin_shufflevector(vr[it], vr[it], 0, 1, 2, 3);
      *(u16x4*)&Vgg[d * VSTR + vj * 8 + 4] =
          __builtin_shufflevector(vr[it], vr[it], 4, 5, 6, 7);
    }
    __syncthreads();
    if (tt < 7) {
      const int m0n = ((tt + 1) * 4 + g4) * 128;
      #pragma unroll
      for (int it = 0; it < 2; ++it) {
        int m = kj * 4 + it * 64;
        kr0[it] = *(const u16x4*)&Qb[KOFF + (h * 32 + 2 * kdp) * 4096 + m0n + m];
        kr1[it] = *(const u16x4*)&Qb[KOFF + (h * 32 + 2 * kdp + 1) * 4096 + m0n + m];
        vr[it] = *(const u16x8*)&Qb[VOFF + (h * 32 + vdd + 16 * it) * 4096 + m0n + vj * 8];
      }
    }
    // wave qw handles chunks {2qw, 2qw+1}; each K/V frag feeds 4 q-subtiles
    #pragma unroll
    for (int jj = 0; jj < 2; ++jj) {
      const int j = qw * 2 + jj;
      bf16x8 kf = *(const bf16x8*)&Kgg[(j * 16 + c) * KSTR + g * 8];
      bf16x4 vf0 = *(const bf16x4*)&Vgg[c * VSTR + j * 16 + g * 4];
      bf16x4 vf1 = *(const bf16x4*)&Vgg[(16 + c) * VSTR + j * 16 + g * 4];
      #pragma unroll
      for (int s = 0; s < 4; ++s) {
        f32x4 z = {0.f, 0.f, 0.f, 0.f};
        f32x4 sv = __builtin_amdgcn_mfma_f32_16x16x32_bf16(kf, qf[s], z, 0, 0, 0);
        unsigned u0 = fbits(fexp2(sv[0]));
        unsigned u1 = fbits(fexp2(sv[1]));
        unsigned u2 = fbits(fexp2(sv[2]));
        unsigned u3 = fbits(fexp2(sv[3]));
        unsigned t0 = u0 & 0xFFFF0000u, t1 = u1 & 0xFFFF0000u;
        unsigned t2 = u2 & 0xFFFF0000u, t3 = u3 & 0xFFFF0000u;
        lsum[s] += (bfloat(t0) + bfloat(t1)) + (bfloat(t2) + bfloat(t3));
        unsigned pk0 = (u0 >> 16) | t1;
        unsigned pk1 = (u2 >> 16) | t3;
        union { unsigned u[2]; bf16x4 v; } pu;
        pu.u[0] = pk0; pu.u[1] = pk1;
        oh[s][0] = pv_mfma(vf0, pu.v, oh[s][0]);
        oh[s][1] = pv_mfma(vf1, pu.v, oh[s][1]);
      }
    }
  }

  // reduce lsum over the 4 key-row groups (g)
  #pragma unroll
  for (int s = 0; s < 4; ++s) {
    lsum[s] += __shfl_xor(lsum[s], 16, 64);
    lsum[s] += __shfl_xor(lsum[s], 32, 64);
  }

  __syncthreads();   // all compute done; staging LDS reusable
  float* OG  = (float*)lds;               // [4][32][66] per-group O accum
  float* lfq = (float*)(lds + 34048);     // [64] final l per query
  float* lf  = (float*)(lds + 36864);     // [16][64] per-wave l partials
  if (l < 16) {
    #pragma unroll
    for (int s = 0; s < 4; ++s)
      lf[(g4 * 4 + qw) * 64 + s * 16 + c] = lsum[s];
  }
  // 4-round in-group accumulation of O partials
  for (int r = 0; r < 4; ++r) {
    if (qw == r) {
      #pragma unroll
      for (int s = 0; s < 4; ++s)
        #pragma unroll
        for (int i = 0; i < 4; ++i) {
          int d0 = 4 * g + i;
          float* p0 = &OG[g4 * 2112 + d0 * 66 + s * 16 + c];
          float* p1 = &OG[g4 * 2112 + (16 + d0) * 66 + s * 16 + c];
          if (r == 0) { *p0 = oh[s][0][i];  *p1 = oh[s][1][i]; }
          else        { *p0 += oh[s][0][i]; *p1 += oh[s][1][i]; }
        }
    }
    __syncthreads();
  }
  if (t < 64) {
    float a = 0.f;
    #pragma unroll
    for (int ww = 0; ww < 16; ++ww) a += lf[ww * 64 + t];
    lfq[t] = a;
  }
  __syncthreads();

  #pragma unroll
  for (int e = t; e < 2048; e += 1024) {
    int d = e & 31, q = e >> 5;
    float s4 = OG[0 * 2112 + d * 66 + q] + OG[1 * 2112 + d * 66 + q] +
               OG[2 * 2112 + d * 66 + q] + OG[3 * 2112 + d * 66 + q];
    float val = s4 / lfq[q];
    unsigned short hi = f2bf(val);
    float hf = bfloat((unsigned)hi << 16);
    int idx = (blockIdx.x * 64 + q) * 128 + h * 32 + d;
    Oth[idx] = hi;
    Otl[idx] = f2bf(val - hf);
  }
}

extern "C" void kernel_launch(void* const* d_in, const int* in_sizes, int n_in,
                              void* d_out, int out_size, void* d_ws, size_t ws_size,
                              hipStream_t stream) {
  const float* xq    = (const float*)d_in[0];
  const float* xkv   = (const float*)d_in[1];
  const float* wqkv  = (const float*)d_in[2];
  const float* wdw   = (const float*)d_in[3];
  const float* wproj = (const float*)d_in[4];
  const float* temp  = (const float*)d_in[5];
  float* out = (float*)d_out;

  char* ws = (char*)d_ws;
  unsigned short* t16  = (unsigned short*)ws;                  // 3*128*4096 bf16 = 3 MB
  unsigned short* qb   = (unsigned short*)(ws + 3145728);      // 3 MB
  unsigned short* xt   = (unsigned short*)(ws + 6291456);      // 2 MB
  unsigned short* wq16 = (unsigned short*)(ws + 8388608);      // 96 KB
  unsigned short* wph  = (unsigned short*)(ws + 8486912);      // 32 KB
  unsigned short* wpl  = (unsigned short*)(ws + 8519680);      // 32 KB
  unsigned short* oth  = (unsigned short*)(ws + 8552448);      // 1 MB
  unsigned short* otl  = (unsigned short*)(ws + 9601024);      // 1 MB

  cast_kernel<<<dim3(260), 256, 0, stream>>>(xq, xkv, wqkv, wproj, xt, wq16, wph, wpl);
  gemm_qkv_kernel<<<dim3(128, 6), 256, 0, stream>>>(xt, wq16, t16);
  dwconv_kernel<<<dim3(384), 256, 0, stream>>>(t16, wdw, temp, qb);
  attn_kernel<<<dim3(64, 4), 1024, 0, stream>>>(qb, oth, otl);
  gemm_proj_kernel<<<dim3(128, 2), 256, 0, stream>>>(oth, otl, wph, wpl, out);
}

// Round 5
// 57.392 us; speedup vs baseline: 1.0863x; 1.0863x over previous
//
#include <hip/hip_runtime.h>

typedef short bf16x4 __attribute__((ext_vector_type(4)));
typedef short bf16x8 __attribute__((ext_vector_type(8)));
typedef float f32x4 __attribute__((ext_vector_type(4)));
typedef unsigned short u16x4 __attribute__((ext_vector_type(4)));
typedef unsigned short u16x8 __attribute__((ext_vector_type(8)));

__device__ __forceinline__ unsigned short f2bf(float f) {
  union { float f; unsigned u; } v; v.f = f;
  unsigned r = v.u + 0x7FFFu + ((v.u >> 16) & 1u);
  return (unsigned short)(r >> 16);
}
__device__ __forceinline__ unsigned fbits(float f) {
  union { float f; unsigned u; } x; x.f = f; return x.u;
}
__device__ __forceinline__ float bfloat(unsigned u) {
  union { unsigned u; float f; } x; x.u = u; return x.f;
}
__device__ __forceinline__ float fexp2(float x) {
#if __has_builtin(__builtin_amdgcn_exp2f)
  return __builtin_amdgcn_exp2f(x);
#else
  return exp2f(x);
#endif
}
__device__ __forceinline__ f32x4 pv_mfma(bf16x4 a, bf16x4 b, f32x4 c) {
#if __has_builtin(__builtin_amdgcn_mfma_f32_16x16x16bf16_1k)
  return __builtin_amdgcn_mfma_f32_16x16x16bf16_1k(a, b, c, 0, 0, 0);
#else
  bf16x8 az = {a[0], a[1], a[2], a[3], 0, 0, 0, 0};
  bf16x8 bz = {b[0], b[1], b[2], b[3], 0, 0, 0, 0};
  return __builtin_amdgcn_mfma_f32_16x16x32_bf16(az, bz, c, 0, 0, 0);
#endif
}

// ---------- cast/transpose: Xq,Xkv [128][4096] f32 -> XT [2][4096][128] bf16,
// ---------- plus weight casts (wqkv -> bf16, wproj -> hi/lo bf16 split).
__global__ __launch_bounds__(256)
void cast_kernel(const float* __restrict__ Xq, const float* __restrict__ Xkv,
                 const float* __restrict__ Wqkv, const float* __restrict__ Wproj,
                 unsigned short* __restrict__ XT, unsigned short* __restrict__ Wq16,
                 unsigned short* __restrict__ Wph, unsigned short* __restrict__ Wpl)
{
  const int b = blockIdx.x, t = threadIdx.x;
  if (b < 256) {
    __shared__ __align__(16) float Tl[64][68];
    const int img = b >> 7, kt = (b >> 6) & 1, nt = b & 63;
    const float* X = img ? Xkv : Xq;
    #pragma unroll
    for (int i = 0; i < 4; ++i) {
      int e = i * 256 + t;
      int r = e >> 4, c4 = (e & 15) * 4;
      *(f32x4*)&Tl[r][c4] = *(const f32x4*)&X[(kt * 64 + r) * 4096 + nt * 64 + c4];
    }
    __syncthreads();
    unsigned short* out = XT + img * (4096 * 128);
    #pragma unroll
    for (int i = 0; i < 2; ++i) {
      int u = i * 256 + t;
      int n = u >> 3, kg = u & 7;
      u16x8 tv;
      #pragma unroll
      for (int j = 0; j < 8; ++j) tv[j] = f2bf(Tl[kg * 8 + j][n]);
      *(u16x8*)&out[(nt * 64 + n) * 128 + kt * 64 + kg * 8] = tv;
    }
  } else {
    const int wb = b - 256;
    if (wb < 3) {
      #pragma unroll 4
      for (int i = 0; i < 64; ++i) {
        int idx = wb * 16384 + i * 256 + t;
        Wq16[idx] = f2bf(Wqkv[idx]);
      }
    } else {
      #pragma unroll 4
      for (int i = 0; i < 64; ++i) {
        int idx = i * 256 + t;
        float v = Wproj[idx];
        unsigned short h = f2bf(v);
        float hf = bfloat((unsigned)h << 16);
        Wph[idx] = h;
        Wpl[idx] = f2bf(v - hf);
      }
    }
  }
}

// ---------- qkv GEMM: all-register MFMA, bf16 output (feeds dwconv) ----------
__global__ __launch_bounds__(256)
void gemm_qkv_kernel(const unsigned short* __restrict__ XT,
                     const unsigned short* __restrict__ Wq16,
                     unsigned short* __restrict__ Y16)
{
  const int t = threadIdx.x;
  const int w = t >> 6, c = t & 15, g = (t & 63) >> 4;
  const int n0 = blockIdx.x * 32;
  const int ob = blockIdx.y;                 // 0..5; ob>=2 -> Xkv
  const int o_base = ob * 64 + w * 16;
  const unsigned short* B = XT + (ob >= 2 ? 4096 * 128 : 0);
  f32x4 acc0 = {0.f, 0.f, 0.f, 0.f}, acc1 = {0.f, 0.f, 0.f, 0.f};
  #pragma unroll
  for (int ks = 0; ks < 4; ++ks) {
    bf16x8 a = *(const bf16x8*)&Wq16[(o_base + c) * 128 + ks * 32 + g * 8];
    bf16x8 b0 = *(const bf16x8*)&B[(n0 + c) * 128 + ks * 32 + g * 8];
    bf16x8 b1 = *(const bf16x8*)&B[(n0 + 16 + c) * 128 + ks * 32 + g * 8];
    acc0 = __builtin_amdgcn_mfma_f32_16x16x32_bf16(a, b0, acc0, 0, 0, 0);
    acc1 = __builtin_amdgcn_mfma_f32_16x16x32_bf16(a, b1, acc1, 0, 0, 0);
  }
  #pragma unroll
  for (int i = 0; i < 4; ++i) {
    Y16[(o_base + 4 * g + i) * 4096 + n0 + c] = f2bf(acc0[i]);
    Y16[(o_base + 4 * g + i) * 4096 + n0 + 16 + c] = f2bf(acc1[i]);
  }
}

// ---------- proj GEMM, split-bf16 (hi+lo) for f32-quality output ----------
__global__ __launch_bounds__(256)
void gemm_proj_kernel(const unsigned short* __restrict__ Oth,
                      const unsigned short* __restrict__ Otl,
                      const unsigned short* __restrict__ Wph,
                      const unsigned short* __restrict__ Wpl, float* __restrict__ Y)
{
  const int t = threadIdx.x;
  const int w = t >> 6, c = t & 15, g = (t & 63) >> 4;
  const int n0 = blockIdx.x * 32;
  const int o_base = blockIdx.y * 64 + w * 16;
  f32x4 acc0 = {0.f, 0.f, 0.f, 0.f}, acc1 = {0.f, 0.f, 0.f, 0.f};
  #pragma unroll
  for (int ks = 0; ks < 4; ++ks) {
    const int ko = ks * 32 + g * 8;
    bf16x8 ah = *(const bf16x8*)&Wph[(o_base + c) * 128 + ko];
    bf16x8 al = *(const bf16x8*)&Wpl[(o_base + c) * 128 + ko];
    bf16x8 bh0 = *(const bf16x8*)&Oth[(n0 + c) * 128 + ko];
    bf16x8 bl0 = *(const bf16x8*)&Otl[(n0 + c) * 128 + ko];
    bf16x8 bh1 = *(const bf16x8*)&Oth[(n0 + 16 + c) * 128 + ko];
    bf16x8 bl1 = *(const bf16x8*)&Otl[(n0 + 16 + c) * 128 + ko];
    acc0 = __builtin_amdgcn_mfma_f32_16x16x32_bf16(al, bh0, acc0, 0, 0, 0);
    acc0 = __builtin_amdgcn_mfma_f32_16x16x32_bf16(ah, bl0, acc0, 0, 0, 0);
    acc0 = __builtin_amdgcn_mfma_f32_16x16x32_bf16(ah, bh0, acc0, 0, 0, 0);
    acc1 = __builtin_amdgcn_mfma_f32_16x16x32_bf16(al, bh1, acc1, 0, 0, 0);
    acc1 = __builtin_amdgcn_mfma_f32_16x16x32_bf16(ah, bl1, acc1, 0, 0, 0);
    acc1 = __builtin_amdgcn_mfma_f32_16x16x32_bf16(ah, bh1, acc1, 0, 0, 0);
  }
  #pragma unroll
  for (int i = 0; i < 4; ++i) {
    Y[(o_base + 4 * g + i) * 4096 + n0 + c] = acc0[i];
    Y[(o_base + 4 * g + i) * 4096 + n0 + 16 + c] = acc1[i];
  }
}

// ------------- depthwise 3x3 SAME on one 64x64 plane per block -------------
__global__ __launch_bounds__(256)
void dwconv_kernel(const unsigned short* __restrict__ T16, const float* __restrict__ Wd,
                   const float* __restrict__ temp, unsigned short* __restrict__ Qb)
{
  __shared__ __align__(16) float P[4096];
  const int jc = blockIdx.x;
  const int t = threadIdx.x;
  const unsigned short* in = T16 + jc * 4096;
  #pragma unroll
  for (int i = 0; i < 2; ++i) {
    u16x8 v = *(const u16x8*)&in[(i * 256 + t) * 8];
    #pragma unroll
    for (int j = 0; j < 8; ++j)
      P[(i * 256 + t) * 8 + j] = bfloat((unsigned)v[j] << 16);
  }
  float w[9];
  #pragma unroll
  for (int k = 0; k < 9; ++k) w[k] = Wd[jc * 9 + k];
  const float scale = (jc < 128) ? temp[jc >> 5] * 1.4426950408889634f : 1.0f;
  __syncthreads();
  unsigned short* out = Qb + jc * 4096;
  #pragma unroll 4
  for (int i = 0; i < 16; ++i) {
    int idx = i * 256 + t;
    int y = idx >> 6, x = idx & 63;
    float acc = 0.f;
    #pragma unroll
    for (int dy = -1; dy <= 1; ++dy) {
      int yy = y + dy;
      if (yy < 0 || yy > 63) continue;
      #pragma unroll
      for (int dx = -1; dx <= 1; ++dx) {
        int xx = x + dx;
        if (xx < 0 || xx > 63) continue;
        acc += w[(dy + 1) * 3 + (dx + 1)] * P[yy * 64 + xx];
      }
    }
    out[idx] = f2bf(acc * scale);
  }
}

// ----------------------- flash attention (bf16 MFMA) -----------------------
// Barrier-free main loop: no LDS staging. K/V are L2-resident (512 KB/head);
// fragments load directly from global. Block = 1024 thr = 16 waves; wave wv
// owns ALL 64 queries (qf[4]) x keys [wv*256, wv*256+256). Epilogue: R4's
// two-stage LDS combine (g4 = wv>>2, qw = wv&3).
#define KOFF (128 * 4096)
#define VOFF (256 * 4096)

__global__ __launch_bounds__(1024, 4)
void attn_kernel(const unsigned short* __restrict__ Qb,
                 unsigned short* __restrict__ Oth, unsigned short* __restrict__ Otl)
{
  __shared__ __align__(16) char lds[40960];
  const int t = threadIdx.x;
  const int wv = t >> 6;          // wave 0..15
  const int g4 = wv >> 2, qw = wv & 3;
  const int l = t & 63;
  const int c = l & 15, g = l >> 4;
  const int h = blockIdx.y;
  const int nq = blockIdx.x * 64;
  const int m0w = wv * 256;       // this wave's key range base

  // 4 Q B-frags: subtile s covers queries nq + s*16 + c
  bf16x8 qf[4];
  #pragma unroll
  for (int s = 0; s < 4; ++s)
    #pragma unroll
    for (int e = 0; e < 8; ++e)
      qf[s][e] = (short)Qb[(h * 32 + g * 8 + e) * 4096 + nq + s * 16 + c];

  f32x4 oh[4][2];
  #pragma unroll
  for (int s = 0; s < 4; ++s) {
    oh[s][0] = (f32x4){0.f, 0.f, 0.f, 0.f};
    oh[s][1] = (f32x4){0.f, 0.f, 0.f, 0.f};
  }
  float lsum[4] = {0.f, 0.f, 0.f, 0.f};

  // loop-invariant per-lane base pointers (imm offsets cover j*32 bytes)
  const unsigned short* Kb = Qb + KOFF + (h * 32 + g * 8) * 4096 + m0w + c;
  const unsigned short* Vb0 = Qb + VOFF + (h * 32 + c) * 4096 + m0w + g * 4;
  const unsigned short* Vb1 = Vb0 + 16 * 4096;

  #pragma unroll 4
  for (int j = 0; j < 16; ++j) {
    bf16x8 kf;
    #pragma unroll
    for (int e = 0; e < 8; ++e)
      kf[e] = (short)Kb[e * 4096 + j * 16];
    bf16x4 vf0 = *(const bf16x4*)&Vb0[j * 16];
    bf16x4 vf1 = *(const bf16x4*)&Vb1[j * 16];
    #pragma unroll
    for (int s = 0; s < 4; ++s) {
      f32x4 z = {0.f, 0.f, 0.f, 0.f};
      f32x4 sv = __builtin_amdgcn_mfma_f32_16x16x32_bf16(kf, qf[s], z, 0, 0, 0);
      unsigned u0 = fbits(fexp2(sv[0]));
      unsigned u1 = fbits(fexp2(sv[1]));
      unsigned u2 = fbits(fexp2(sv[2]));
      unsigned u3 = fbits(fexp2(sv[3]));
      unsigned t0 = u0 & 0xFFFF0000u, t1 = u1 & 0xFFFF0000u;
      unsigned t2 = u2 & 0xFFFF0000u, t3 = u3 & 0xFFFF0000u;
      lsum[s] += (bfloat(t0) + bfloat(t1)) + (bfloat(t2) + bfloat(t3));
      union { unsigned u[2]; bf16x4 v; } pu;
      pu.u[0] = __builtin_amdgcn_perm(u1, u0, 0x07060302);  // [u1.hi16|u0.hi16]
      pu.u[1] = __builtin_amdgcn_perm(u3, u2, 0x07060302);
      oh[s][0] = pv_mfma(vf0, pu.v, oh[s][0]);
      oh[s][1] = pv_mfma(vf1, pu.v, oh[s][1]);
    }
  }

  // reduce lsum over the 4 key-row groups (g)
  #pragma unroll
  for (int s = 0; s < 4; ++s) {
    lsum[s] += __shfl_xor(lsum[s], 16, 64);
    lsum[s] += __shfl_xor(lsum[s], 32, 64);
  }

  __syncthreads();
  float* OG  = (float*)lds;               // [4][32][66] per-group O accum
  float* lfq = (float*)(lds + 34048);     // [64] final l per query
  float* lf  = (float*)(lds + 36864);     // [16][64] per-wave l partials
  if (l < 16) {
    #pragma unroll
    for (int s = 0; s < 4; ++s)
      lf[(g4 * 4 + qw) * 64 + s * 16 + c] = lsum[s];
  }
  // 4-round in-group accumulation of O partials
  for (int r = 0; r < 4; ++r) {
    if (qw == r) {
      #pragma unroll
      for (int s = 0; s < 4; ++s)
        #pragma unroll
        for (int i = 0; i < 4; ++i) {
          int d0 = 4 * g + i;
          float* p0 = &OG[g4 * 2112 + d0 * 66 + s * 16 + c];
          float* p1 = &OG[g4 * 2112 + (16 + d0) * 66 + s * 16 + c];
          if (r == 0) { *p0 = oh[s][0][i];  *p1 = oh[s][1][i]; }
          else        { *p0 += oh[s][0][i]; *p1 += oh[s][1][i]; }
        }
    }
    __syncthreads();
  }
  if (t < 64) {
    float a = 0.f;
    #pragma unroll
    for (int ww = 0; ww < 16; ++ww) a += lf[ww * 64 + t];
    lfq[t] = a;
  }
  __syncthreads();

  #pragma unroll
  for (int e = t; e < 2048; e += 1024) {
    int d = e & 31, q = e >> 5;
    float s4 = OG[0 * 2112 + d * 66 + q] + OG[1 * 2112 + d * 66 + q] +
               OG[2 * 2112 + d * 66 + q] + OG[3 * 2112 + d * 66 + q];
    float val = s4 / lfq[q];
    unsigned short hi = f2bf(val);
    float hf = bfloat((unsigned)hi << 16);
    int idx = (blockIdx.x * 64 + q) * 128 + h * 32 + d;
    Oth[idx] = hi;
    Otl[idx] = f2bf(val - hf);
  }
}

extern "C" void kernel_launch(void* const* d_in, const int* in_sizes, int n_in,
                              void* d_out, int out_size, void* d_ws, size_t ws_size,
                              hipStream_t stream) {
  const float* xq    = (const float*)d_in[0];
  const float* xkv   = (const float*)d_in[1];
  const float* wqkv  = (const float*)d_in[2];
  const float* wdw   = (const float*)d_in[3];
  const float* wproj = (const float*)d_in[4];
  const float* temp  = (const float*)d_in[5];
  float* out = (float*)d_out;

  char* ws = (char*)d_ws;
  unsigned short* t16  = (unsigned short*)ws;                  // 3 MB
  unsigned short* qb   = (unsigned short*)(ws + 3145728);      // 3 MB
  unsigned short* xt   = (unsigned short*)(ws + 6291456);      // 2 MB
  unsigned short* wq16 = (unsigned short*)(ws + 8388608);      // 96 KB
  unsigned short* wph  = (unsigned short*)(ws + 8486912);      // 32 KB
  unsigned short* wpl  = (unsigned short*)(ws + 8519680);      // 32 KB
  unsigned short* oth  = (unsigned short*)(ws + 8552448);      // 1 MB
  unsigned short* otl  = (unsigned short*)(ws + 9601024);      // 1 MB

  cast_kernel<<<dim3(260), 256, 0, stream>>>(xq, xkv, wqkv, wproj, xt, wq16, wph, wpl);
  gemm_qkv_kernel<<<dim3(128, 6), 256, 0, stream>>>(xt, wq16, t16);
  dwconv_kernel<<<dim3(384), 256, 0, stream>>>(t16, wdw, temp, qb);
  attn_kernel<<<dim3(64, 4), 1024, 0, stream>>>(qb, oth, otl);
  gemm_proj_kernel<<<dim3(128, 2), 256, 0, stream>>>(oth, otl, wph, wpl, out);
}

// Round 6
// 57.385 us; speedup vs baseline: 1.0864x; 1.0001x over previous
//
#include <hip/hip_runtime.h>

typedef short bf16x4 __attribute__((ext_vector_type(4)));
typedef short bf16x8 __attribute__((ext_vector_type(8)));
typedef float f32x4 __attribute__((ext_vector_type(4)));
typedef unsigned short u16x4 __attribute__((ext_vector_type(4)));
typedef unsigned short u16x8 __attribute__((ext_vector_type(8)));

__device__ __forceinline__ unsigned short f2bf(float f) {
  union { float f; unsigned u; } v; v.f = f;
  unsigned r = v.u + 0x7FFFu + ((v.u >> 16) & 1u);
  return (unsigned short)(r >> 16);
}
__device__ __forceinline__ unsigned fbits(float f) {
  union { float f; unsigned u; } x; x.f = f; return x.u;
}
__device__ __forceinline__ float bfloat(unsigned u) {
  union { unsigned u; float f; } x; x.u = u; return x.f;
}
__device__ __forceinline__ float fexp2(float x) {
#if __has_builtin(__builtin_amdgcn_exp2f)
  return __builtin_amdgcn_exp2f(x);
#else
  return exp2f(x);
#endif
}
__device__ __forceinline__ f32x4 pv_mfma(bf16x4 a, bf16x4 b, f32x4 c) {
#if __has_builtin(__builtin_amdgcn_mfma_f32_16x16x16bf16_1k)
  return __builtin_amdgcn_mfma_f32_16x16x16bf16_1k(a, b, c, 0, 0, 0);
#else
  bf16x8 az = {a[0], a[1], a[2], a[3], 0, 0, 0, 0};
  bf16x8 bz = {b[0], b[1], b[2], b[3], 0, 0, 0, 0};
  return __builtin_amdgcn_mfma_f32_16x16x32_bf16(az, bz, c, 0, 0, 0);
#endif
}

// ---------- cast/transpose: Xq,Xkv [128][4096] f32 -> XT [2][4096][128] bf16,
// ---------- plus weight casts (wqkv -> bf16, wproj -> hi/lo bf16 split).
__global__ __launch_bounds__(256)
void cast_kernel(const float* __restrict__ Xq, const float* __restrict__ Xkv,
                 const float* __restrict__ Wqkv, const float* __restrict__ Wproj,
                 unsigned short* __restrict__ XT, unsigned short* __restrict__ Wq16,
                 unsigned short* __restrict__ Wph, unsigned short* __restrict__ Wpl)
{
  const int b = blockIdx.x, t = threadIdx.x;
  if (b < 256) {
    __shared__ __align__(16) float Tl[64][68];
    const int img = b >> 7, kt = (b >> 6) & 1, nt = b & 63;
    const float* X = img ? Xkv : Xq;
    #pragma unroll
    for (int i = 0; i < 4; ++i) {
      int e = i * 256 + t;
      int r = e >> 4, c4 = (e & 15) * 4;
      *(f32x4*)&Tl[r][c4] = *(const f32x4*)&X[(kt * 64 + r) * 4096 + nt * 64 + c4];
    }
    __syncthreads();
    unsigned short* out = XT + img * (4096 * 128);
    #pragma unroll
    for (int i = 0; i < 2; ++i) {
      int u = i * 256 + t;
      int n = u >> 3, kg = u & 7;
      u16x8 tv;
      #pragma unroll
      for (int j = 0; j < 8; ++j) tv[j] = f2bf(Tl[kg * 8 + j][n]);
      *(u16x8*)&out[(nt * 64 + n) * 128 + kt * 64 + kg * 8] = tv;
    }
  } else {
    const int wb = b - 256;
    if (wb < 3) {
      #pragma unroll 4
      for (int i = 0; i < 64; ++i) {
        int idx = wb * 16384 + i * 256 + t;
        Wq16[idx] = f2bf(Wqkv[idx]);
      }
    } else {
      #pragma unroll 4
      for (int i = 0; i < 64; ++i) {
        int idx = i * 256 + t;
        float v = Wproj[idx];
        unsigned short h = f2bf(v);
        float hf = bfloat((unsigned)h << 16);
        Wph[idx] = h;
        Wpl[idx] = f2bf(v - hf);
      }
    }
  }
}

// ---------- qkv GEMM: all-register MFMA, bf16 output (feeds dwconv) ----------
__global__ __launch_bounds__(256)
void gemm_qkv_kernel(const unsigned short* __restrict__ XT,
                     const unsigned short* __restrict__ Wq16,
                     unsigned short* __restrict__ Y16)
{
  const int t = threadIdx.x;
  const int w = t >> 6, c = t & 15, g = (t & 63) >> 4;
  const int n0 = blockIdx.x * 32;
  const int ob = blockIdx.y;                 // 0..5; ob>=2 -> Xkv
  const int o_base = ob * 64 + w * 16;
  const unsigned short* B = XT + (ob >= 2 ? 4096 * 128 : 0);
  f32x4 acc0 = {0.f, 0.f, 0.f, 0.f}, acc1 = {0.f, 0.f, 0.f, 0.f};
  #pragma unroll
  for (int ks = 0; ks < 4; ++ks) {
    bf16x8 a = *(const bf16x8*)&Wq16[(o_base + c) * 128 + ks * 32 + g * 8];
    bf16x8 b0 = *(const bf16x8*)&B[(n0 + c) * 128 + ks * 32 + g * 8];
    bf16x8 b1 = *(const bf16x8*)&B[(n0 + 16 + c) * 128 + ks * 32 + g * 8];
    acc0 = __builtin_amdgcn_mfma_f32_16x16x32_bf16(a, b0, acc0, 0, 0, 0);
    acc1 = __builtin_amdgcn_mfma_f32_16x16x32_bf16(a, b1, acc1, 0, 0, 0);
  }
  #pragma unroll
  for (int i = 0; i < 4; ++i) {
    Y16[(o_base + 4 * g + i) * 4096 + n0 + c] = f2bf(acc0[i]);
    Y16[(o_base + 4 * g + i) * 4096 + n0 + 16 + c] = f2bf(acc1[i]);
  }
}

// ---------- proj GEMM, split-bf16 (hi+lo) for f32-quality output ----------
__global__ __launch_bounds__(256)
void gemm_proj_kernel(const unsigned short* __restrict__ Oth,
                      const unsigned short* __restrict__ Otl,
                      const unsigned short* __restrict__ Wph,
                      const unsigned short* __restrict__ Wpl, float* __restrict__ Y)
{
  const int t = threadIdx.x;
  const int w = t >> 6, c = t & 15, g = (t & 63) >> 4;
  const int n0 = blockIdx.x * 32;
  const int o_base = blockIdx.y * 64 + w * 16;
  f32x4 acc0 = {0.f, 0.f, 0.f, 0.f}, acc1 = {0.f, 0.f, 0.f, 0.f};
  #pragma unroll
  for (int ks = 0; ks < 4; ++ks) {
    const int ko = ks * 32 + g * 8;
    bf16x8 ah = *(const bf16x8*)&Wph[(o_base + c) * 128 + ko];
    bf16x8 al = *(const bf16x8*)&Wpl[(o_base + c) * 128 + ko];
    bf16x8 bh0 = *(const bf16x8*)&Oth[(n0 + c) * 128 + ko];
    bf16x8 bl0 = *(const bf16x8*)&Otl[(n0 + c) * 128 + ko];
    bf16x8 bh1 = *(const bf16x8*)&Oth[(n0 + 16 + c) * 128 + ko];
    bf16x8 bl1 = *(const bf16x8*)&Otl[(n0 + 16 + c) * 128 + ko];
    acc0 = __builtin_amdgcn_mfma_f32_16x16x32_bf16(al, bh0, acc0, 0, 0, 0);
    acc0 = __builtin_amdgcn_mfma_f32_16x16x32_bf16(ah, bl0, acc0, 0, 0, 0);
    acc0 = __builtin_amdgcn_mfma_f32_16x16x32_bf16(ah, bh0, acc0, 0, 0, 0);
    acc1 = __builtin_amdgcn_mfma_f32_16x16x32_bf16(al, bh1, acc1, 0, 0, 0);
    acc1 = __builtin_amdgcn_mfma_f32_16x16x32_bf16(ah, bl1, acc1, 0, 0, 0);
    acc1 = __builtin_amdgcn_mfma_f32_16x16x32_bf16(ah, bh1, acc1, 0, 0, 0);
  }
  #pragma unroll
  for (int i = 0; i < 4; ++i) {
    Y[(o_base + 4 * g + i) * 4096 + n0 + c] = acc0[i];
    Y[(o_base + 4 * g + i) * 4096 + n0 + 16 + c] = acc1[i];
  }
}

// ------------- depthwise 3x3 SAME on one 64x64 plane per block -------------
// bf16 in; q,k outputs go TRANSPOSED to Qt/Kt [h][pos][32] (scatter u16),
// v stays channel-major in Vb. temp*log2e folded into q.
__global__ __launch_bounds__(256)
void dwconv_kernel(const unsigned short* __restrict__ T16, const float* __restrict__ Wd,
                   const float* __restrict__ temp, unsigned short* __restrict__ Qt,
                   unsigned short* __restrict__ Kt, unsigned short* __restrict__ Vb)
{
  __shared__ __align__(16) float P[4096];
  const int jc = blockIdx.x;
  const int t = threadIdx.x;
  const unsigned short* in = T16 + jc * 4096;
  #pragma unroll
  for (int i = 0; i < 2; ++i) {
    u16x8 v = *(const u16x8*)&in[(i * 256 + t) * 8];
    #pragma unroll
    for (int j = 0; j < 8; ++j)
      P[(i * 256 + t) * 8 + j] = bfloat((unsigned)v[j] << 16);
  }
  float w[9];
  #pragma unroll
  for (int k = 0; k < 9; ++k) w[k] = Wd[jc * 9 + k];
  const float scale = (jc < 128) ? temp[jc >> 5] * 1.4426950408889634f : 1.0f;
  __syncthreads();

  const int hh = (jc >> 5) & 3, dd = jc & 31;
  unsigned short* outT = (jc < 128 ? Qt : Kt) + (hh * 4096) * 32 + dd;
  unsigned short* outV = Vb + (jc - 256) * 4096;
  const bool is_v = (jc >= 256);

  #pragma unroll 4
  for (int i = 0; i < 16; ++i) {
    int idx = i * 256 + t;
    int y = idx >> 6, x = idx & 63;
    float acc = 0.f;
    #pragma unroll
    for (int dy = -1; dy <= 1; ++dy) {
      int yy = y + dy;
      if (yy < 0 || yy > 63) continue;
      #pragma unroll
      for (int dx = -1; dx <= 1; ++dx) {
        int xx = x + dx;
        if (xx < 0 || xx > 63) continue;
        acc += w[(dy + 1) * 3 + (dx + 1)] * P[yy * 64 + xx];
      }
    }
    unsigned short r = f2bf(acc * scale);
    if (is_v) outV[idx] = r;
    else      outT[idx * 32] = r;
  }
}

// ----------------------- flash attention (bf16 MFMA) -----------------------
// Barrier-free main loop, K/V L2-resident, Qt/Kt pre-transposed [h][pos][32]:
// Q and K fragments are single coalesced b128 loads. Block = 16 waves; wave
// owns all 64 queries x its private 256-key range. Two-stage LDS epilogue.
__global__ __launch_bounds__(1024, 4)
void attn_kernel(const unsigned short* __restrict__ Qt,
                 const unsigned short* __restrict__ Kt,
                 const unsigned short* __restrict__ Vb,
                 unsigned short* __restrict__ Oth, unsigned short* __restrict__ Otl)
{
  __shared__ __align__(16) char lds[40960];
  const int t = threadIdx.x;
  const int wv = t >> 6;          // wave 0..15
  const int g4 = wv >> 2, qw = wv & 3;
  const int l = t & 63;
  const int c = l & 15, g = l >> 4;
  const int h = blockIdx.y;
  const int nq = blockIdx.x * 64;
  const int m0w = wv * 256;       // this wave's key range base

  // 4 Q B-frags: single b128 each from Qt[h][n][d]
  bf16x8 qf[4];
  #pragma unroll
  for (int s = 0; s < 4; ++s)
    qf[s] = *(const bf16x8*)&Qt[(h * 4096 + nq + s * 16 + c) * 32 + g * 8];

  f32x4 oh[4][2];
  #pragma unroll
  for (int s = 0; s < 4; ++s) {
    oh[s][0] = (f32x4){0.f, 0.f, 0.f, 0.f};
    oh[s][1] = (f32x4){0.f, 0.f, 0.f, 0.f};
  }
  float lsum[4] = {0.f, 0.f, 0.f, 0.f};

  const unsigned short* Kb  = Kt + (h * 4096 + m0w + c) * 32 + g * 8;
  const unsigned short* Vb0 = Vb + (h * 32 + c) * 4096 + m0w + g * 4;
  const unsigned short* Vb1 = Vb0 + 16 * 4096;

  #pragma unroll 4
  for (int j = 0; j < 16; ++j) {
    bf16x8 kf = *(const bf16x8*)&Kb[j * 512];
    bf16x4 vf0 = *(const bf16x4*)&Vb0[j * 16];
    bf16x4 vf1 = *(const bf16x4*)&Vb1[j * 16];
    #pragma unroll
    for (int s = 0; s < 4; ++s) {
      f32x4 z = {0.f, 0.f, 0.f, 0.f};
      f32x4 sv = __builtin_amdgcn_mfma_f32_16x16x32_bf16(kf, qf[s], z, 0, 0, 0);
      float e0 = fexp2(sv[0]);
      float e1 = fexp2(sv[1]);
      float e2 = fexp2(sv[2]);
      float e3 = fexp2(sv[3]);
      lsum[s] += (e0 + e1) + (e2 + e3);
      union { unsigned u[2]; bf16x4 v; } pu;
      pu.u[0] = __builtin_amdgcn_perm(fbits(e1), fbits(e0), 0x07060302);
      pu.u[1] = __builtin_amdgcn_perm(fbits(e3), fbits(e2), 0x07060302);
      oh[s][0] = pv_mfma(vf0, pu.v, oh[s][0]);
      oh[s][1] = pv_mfma(vf1, pu.v, oh[s][1]);
    }
  }

  // reduce lsum over the 4 key-row groups (g)
  #pragma unroll
  for (int s = 0; s < 4; ++s) {
    lsum[s] += __shfl_xor(lsum[s], 16, 64);
    lsum[s] += __shfl_xor(lsum[s], 32, 64);
  }

  __syncthreads();
  float* OG  = (float*)lds;               // [4][32][66] per-group O accum
  float* lfq = (float*)(lds + 34048);     // [64] final l per query
  float* lf  = (float*)(lds + 36864);     // [16][64] per-wave l partials
  if (l < 16) {
    #pragma unroll
    for (int s = 0; s < 4; ++s)
      lf[(g4 * 4 + qw) * 64 + s * 16 + c] = lsum[s];
  }
  for (int r = 0; r < 4; ++r) {
    if (qw == r) {
      #pragma unroll
      for (int s = 0; s < 4; ++s)
        #pragma unroll
        for (int i = 0; i < 4; ++i) {
          int d0 = 4 * g + i;
          float* p0 = &OG[g4 * 2112 + d0 * 66 + s * 16 + c];
          float* p1 = &OG[g4 * 2112 + (16 + d0) * 66 + s * 16 + c];
          if (r == 0) { *p0 = oh[s][0][i];  *p1 = oh[s][1][i]; }
          else        { *p0 += oh[s][0][i]; *p1 += oh[s][1][i]; }
        }
    }
    __syncthreads();
  }
  if (t < 64) {
    float a = 0.f;
    #pragma unroll
    for (int ww = 0; ww < 16; ++ww) a += lf[ww * 64 + t];
    lfq[t] = a;
  }
  __syncthreads();

  #pragma unroll
  for (int e = t; e < 2048; e += 1024) {
    int d = e & 31, q = e >> 5;
    float s4 = OG[0 * 2112 + d * 66 + q] + OG[1 * 2112 + d * 66 + q] +
               OG[2 * 2112 + d * 66 + q] + OG[3 * 2112 + d * 66 + q];
    float val = s4 / lfq[q];
    unsigned short hi = f2bf(val);
    float hf = bfloat((unsigned)hi << 16);
    int idx = (blockIdx.x * 64 + q) * 128 + h * 32 + d;
    Oth[idx] = hi;
    Otl[idx] = f2bf(val - hf);
  }
}

extern "C" void kernel_launch(void* const* d_in, const int* in_sizes, int n_in,
                              void* d_out, int out_size, void* d_ws, size_t ws_size,
                              hipStream_t stream) {
  const float* xq    = (const float*)d_in[0];
  const float* xkv   = (const float*)d_in[1];
  const float* wqkv  = (const float*)d_in[2];
  const float* wdw   = (const float*)d_in[3];
  const float* wproj = (const float*)d_in[4];
  const float* temp  = (const float*)d_in[5];
  float* out = (float*)d_out;

  char* ws = (char*)d_ws;
  unsigned short* t16  = (unsigned short*)ws;                  // 3 MB
  unsigned short* xt   = (unsigned short*)(ws + 3145728);      // 2 MB
  unsigned short* wq16 = (unsigned short*)(ws + 5242880);      // 96 KB
  unsigned short* wph  = (unsigned short*)(ws + 5341184);      // 32 KB
  unsigned short* wpl  = (unsigned short*)(ws + 5373952);      // 32 KB
  unsigned short* qt   = (unsigned short*)(ws + 5406720);      // 1 MB
  unsigned short* kt   = (unsigned short*)(ws + 6455296);      // 1 MB
  unsigned short* vb   = (unsigned short*)(ws + 7503872);      // 1 MB
  unsigned short* oth  = (unsigned short*)(ws + 8552448);      // 1 MB
  unsigned short* otl  = (unsigned short*)(ws + 9601024);      // 1 MB

  cast_kernel<<<dim3(260), 256, 0, stream>>>(xq, xkv, wqkv, wproj, xt, wq16, wph, wpl);
  gemm_qkv_kernel<<<dim3(128, 6), 256, 0, stream>>>(xt, wq16, t16);
  dwconv_kernel<<<dim3(384), 256, 0, stream>>>(t16, wdw, temp, qt, kt, vb);
  attn_kernel<<<dim3(64, 4), 1024, 0, stream>>>(qt, kt, vb, oth, otl);
  gemm_proj_kernel<<<dim3(128, 2), 256, 0, stream>>>(oth, otl, wph, wpl, out);
}